// Round 5
// baseline (171.995 us; speedup 1.0000x reference)
//
#include <hip/hip_runtime.h>

#define BB 16
#define NN 2048
#define DIN 160
#define IS 32
#define NCAT 64
#define EMBD 64
#define NCTX 2047

// ---------------------------------------------------------------------------
// K1: per-tile partial G = xq.xq^T (32x32), K = xcat.xq^T (64x32) -> Pg/Pk.
// The LAST block to finish for each batch b (device-scope atomic counter)
// reduces the 16 partials and runs the tiny per-batch matrix chain:
//   C0 = emb.K;  for l: W += s*diag(a_l)*C; C += M.(s*diag(a_l)*C.G) (l<2)
//   U = emb^T.W -> Ubuf[b]
// Grid 256 = 16 b x 16 tiles of 128 columns. Block 256.
// ---------------------------------------------------------------------------
__global__ __launch_bounds__(256) void k_gram_chain(
    const float* __restrict__ x, const float* __restrict__ alpha,
    const float* __restrict__ kp, const float* __restrict__ emb,
    const float* __restrict__ Mm,
    float* __restrict__ Pg, float* __restrict__ Pk,
    float* __restrict__ Ubuf, int* __restrict__ cnt)
{
    __shared__ float xs[128][100];  // [n-local][row r<96]
    const int t = threadIdx.x;
    const int blk = blockIdx.x;
    const int b = blk >> 4;
    const int tile = blk & 15;
    const int n0 = tile << 7;
    const float* xb = x + (size_t)b * DIN * NN;

    // stage rows 0..95 of the 128-column slab (transposed into LDS)
    for (int idx = t; idx < 96 * 32; idx += 256) {
        const int r = idx >> 5;
        const int m4 = (idx & 31) << 2;
        float4 v = *(const float4*)&xb[r * NN + n0 + m4];
        xs[m4 + 0][r] = v.x; xs[m4 + 1][r] = v.y;
        xs[m4 + 2][r] = v.z; xs[m4 + 3][r] = v.w;
    }
    __syncthreads();

    const int nlim = (tile == 15) ? 127 : 128;  // exclude global column 2047
    const int i = t >> 3;          // 0..31
    const int d0 = (t & 7) << 2;   // 0,4,..,28
    float4 g = {0,0,0,0}, k0 = {0,0,0,0}, k1 = {0,0,0,0};
#pragma unroll 2
    for (int m = 0; m < nlim; m++) {
        float4 q = *(const float4*)&xs[m][d0];
        const float a  = xs[m][i];        // xq row i
        const float c0 = xs[m][32 + i];   // xcat row i
        const float c1 = xs[m][64 + i];   // xcat row i+32
        g.x  += a  * q.x; g.y  += a  * q.y; g.z  += a  * q.z; g.w  += a  * q.w;
        k0.x += c0 * q.x; k0.y += c0 * q.y; k0.z += c0 * q.z; k0.w += c0 * q.w;
        k1.x += c1 * q.x; k1.y += c1 * q.y; k1.z += c1 * q.z; k1.w += c1 * q.w;
    }
    *(float4*)&Pg[(size_t)blk * 1024 + i * 32 + d0] = g;
    float* pk = Pk + (size_t)blk * 2048;
    *(float4*)&pk[i * 32 + d0] = k0;
    *(float4*)&pk[(i + 32) * 32 + d0] = k1;

    // ---- release partials; last block for this b proceeds to the chain ----
    __shared__ int lastflag;
    __threadfence();  // each thread's partial stores -> device-visible
    __syncthreads();
    if (t == 0) lastflag = (atomicAdd(&cnt[b], 1) == 15);
    __syncthreads();
    if (!lastflag) return;
    __threadfence();  // acquire: see all 16 tiles' partials

    __shared__ float G_s[32][36];
    __shared__ float K_s[64][36];
    __shared__ float C_s[64][36];
    __shared__ float W_s[64][36];
    __shared__ float T_s[64][36];

    for (int idx = t; idx < 1024; idx += 256) {
        float s = 0.f;
#pragma unroll
        for (int gg = 0; gg < 16; gg++) s += Pg[((size_t)(b * 16 + gg)) * 1024 + idx];
        G_s[idx >> 5][idx & 31] = s;
    }
    for (int idx = t; idx < 2048; idx += 256) {
        float s = 0.f;
#pragma unroll
        for (int gg = 0; gg < 16; gg++) s += Pk[((size_t)(b * 16 + gg)) * 2048 + idx];
        K_s[idx >> 5][idx & 31] = s;
    }
    __syncthreads();

    const int r  = t >> 2;         // 0..63
    const int dd = (t & 3) << 3;   // 0,8,16,24

    // C0 = emb . K
    {
        const float* er = emb + r * EMBD;
        float acc[8];
#pragma unroll
        for (int j = 0; j < 8; j++) acc[j] = 0.f;
        for (int c = 0; c < 64; c++) {
            const float e = er[c];
#pragma unroll
            for (int j = 0; j < 8; j++) acc[j] += e * K_s[c][dd + j];
        }
#pragma unroll
        for (int j = 0; j < 8; j++) C_s[r][dd + j] = acc[j];
    }
    __syncthreads();

    const float scale = kp[0] * (1.f / (float)NCTX);
    for (int l = 0; l < 3; l++) {
        const float f = scale * alpha[l * EMBD + r];
#pragma unroll
        for (int j = 0; j < 8; j++) {
            const float w = f * C_s[r][dd + j];
            if (l == 0) W_s[r][dd + j] = w; else W_s[r][dd + j] += w;
        }
        if (l < 2) {
            float tacc[8];
#pragma unroll
            for (int j = 0; j < 8; j++) tacc[j] = 0.f;
            for (int d = 0; d < 32; d++) {
                const float cv = C_s[r][d];
#pragma unroll
                for (int j = 0; j < 8; j++) tacc[j] += cv * G_s[d][dd + j];
            }
#pragma unroll
            for (int j = 0; j < 8; j++) T_s[r][dd + j] = f * tacc[j];
            __syncthreads();
            const float* Mr = Mm + r * EMBD;
            float uacc[8];
#pragma unroll
            for (int j = 0; j < 8; j++) uacc[j] = 0.f;
            for (int jj = 0; jj < 64; jj++) {
                const float mv = Mr[jj];
#pragma unroll
                for (int j = 0; j < 8; j++) uacc[j] += mv * T_s[jj][dd + j];
            }
#pragma unroll
            for (int j = 0; j < 8; j++) C_s[r][dd + j] += uacc[j];
            __syncthreads();
        }
    }
    __syncthreads();

    // U[c][d] = sum_e emb[e][c] * W[e][d], c = r
    {
        float acc[8];
#pragma unroll
        for (int j = 0; j < 8; j++) acc[j] = 0.f;
        for (int e = 0; e < 64; e++) {
            const float ev = emb[e * EMBD + r];
#pragma unroll
            for (int j = 0; j < 8; j++) acc[j] += ev * W_s[e][dd + j];
        }
        float* Ur = Ubuf + (size_t)b * 2048 + r * 32 + dd;
#pragma unroll
        for (int j = 0; j < 8; j++) Ur[j] = acc[j];
    }
}

// ---------------------------------------------------------------------------
// K2: logits[:,n] = emb^T.x_tail[:,n] + U.xq[:,n]; softmax.
// Grid 256 = 16 b x 16 tiles; block 256: t = h*128+nl, h = c-half.
// ---------------------------------------------------------------------------
__global__ __launch_bounds__(256) void k_out(const float* __restrict__ x,
                                             const float* __restrict__ emb,
                                             const float* __restrict__ Ubuf,
                                             float* __restrict__ out) {
    __shared__ float lg_s[128][68];
    const int t = threadIdx.x;
    const int blk = blockIdx.x;
    const int b = blk >> 4;
    const int tile = blk & 15;
    const int h = t >> 7;
    const int nl = t & 127;
    const int n = (tile << 7) + nl;
    const int c0 = h << 5;
    const float* xb = x + (size_t)b * DIN * NN;

    float xq[IS];
#pragma unroll
    for (int d = 0; d < IS; d++) xq[d] = xb[d * NN + n];

    float lg[32];
    const float* Ub = Ubuf + (size_t)b * 2048;
#pragma unroll 4
    for (int cl = 0; cl < 32; cl++) {
        const float* Ur = Ub + (c0 + cl) * 32;  // wave-uniform -> s_load
        float s = 0.f;
#pragma unroll
        for (int k = 0; k < 8; k++) {
            float4 u = *(const float4*)&Ur[4 * k];
            s += u.x * xq[4*k] + u.y * xq[4*k+1] + u.z * xq[4*k+2] + u.w * xq[4*k+3];
        }
        lg[cl] = s;
    }
    for (int e = 0; e < 64; e++) {
        const float tv = xb[(IS + NCAT + e) * NN + n];
        const float* er = emb + e * EMBD + c0;  // wave-uniform
#pragma unroll
        for (int cl = 0; cl < 32; cl++) lg[cl] += er[cl] * tv;
    }

    const size_t base = ((size_t)b * NN + n) * (size_t)NCAT;
    float* lo = out + base + c0;
#pragma unroll
    for (int k = 0; k < 8; k++) {
        float4 v = {lg[4*k], lg[4*k+1], lg[4*k+2], lg[4*k+3]};
        *(float4*)&lo[4*k] = v;
        *(float4*)&lg_s[nl][c0 + 4*k] = v;
    }
    __syncthreads();

    const int o0 = (1 - h) << 5;
    float mx = lg[0];
#pragma unroll
    for (int cl = 1; cl < 32; cl++) mx = fmaxf(mx, lg[cl]);
    float og[32];
#pragma unroll
    for (int k = 0; k < 8; k++) {
        float4 v = *(const float4*)&lg_s[nl][o0 + 4*k];
        og[4*k] = v.x; og[4*k+1] = v.y; og[4*k+2] = v.z; og[4*k+3] = v.w;
    }
#pragma unroll
    for (int cl = 0; cl < 32; cl++) mx = fmaxf(mx, og[cl]);

    float sum = 0.f;
#pragma unroll
    for (int cl = 0; cl < 32; cl++) {
        lg[cl] = __expf(lg[cl] - mx);
        sum += lg[cl];
    }
#pragma unroll
    for (int cl = 0; cl < 32; cl++) sum += __expf(og[cl] - mx);

    const float inv = 1.f / sum;
    float* po = out + (size_t)BB * NN * NCAT + base + c0;
#pragma unroll
    for (int k = 0; k < 8; k++) {
        float4 v = {lg[4*k]*inv, lg[4*k+1]*inv, lg[4*k+2]*inv, lg[4*k+3]*inv};
        *(float4*)&po[4*k] = v;
    }
}

extern "C" void kernel_launch(void* const* d_in, const int* in_sizes, int n_in,
                              void* d_out, int out_size, void* d_ws, size_t ws_size,
                              hipStream_t stream) {
    const float* x     = (const float*)d_in[0];
    const float* alpha = (const float*)d_in[1];
    const float* kp    = (const float*)d_in[2];
    const float* emb   = (const float*)d_in[3];
    const float* Mmat  = (const float*)d_in[4];
    float* out = (float*)d_out;

    float* Pg   = (float*)d_ws;                    // 256*1024
    float* Pk   = Pg + (size_t)256 * 1024;         // 256*2048
    float* Ubuf = Pk + (size_t)256 * 2048;         // 16*2048
    int*   cnt  = (int*)(Ubuf + (size_t)16 * 2048);

    hipMemsetAsync(cnt, 0, BB * sizeof(int), stream);
    k_gram_chain<<<256, 256, 0, stream>>>(x, alpha, kp, emb, Mmat, Pg, Pk, Ubuf, cnt);
    k_out<<<256, 256, 0, stream>>>(x, emb, Ubuf, out);
}